// Round 2
// baseline (229.218 us; speedup 1.0000x reference)
//
#include <hip/hip_runtime.h>

// Bidirectional GRU (H=32, input=1, B=2048, T=512) + MLP head, fully fused.
//
// Reference takes out[:, -1, :] = concat(h_fwd after T steps, h_bwd after ONE
// step from h0=0 on x[T-1]) -> only the forward scan is sequential; W_hh_b is
// entirely unused.
//
// R13: one row per 64-lane wave, K-split halves, 2 waves/SIMD.
//
// Model (R8..R12): wall 532 cyc/step = ~340 issue + ~190 stall at 1 wave/SIMD;
// the stall (h LDS round-trip + chain latency) is unhidable with one wave.
// R12 proved trading stall for issue loses (~6.4 cyc per chained DPP op).
// R13 instead halves PER-WAVE dot issue and doubles waves:
//   * 2048 rows -> 2048 waves (one row per wave) = 2 waves/SIMD. Each wave's
//     stall hides under the other wave's issue; per-SIMD dot issue unchanged.
//   * K-split: lane g (low) holds h[0:16], computes k-low partials of r,z,n
//     for output g (24 fdot2); lane g+32 holds h[16:32], k-high partials.
//   * Cross-half combine via v_permlane32_swap_b32: swap(x,x) = (row0-bcast,
//     row1-bcast) in one full-rate VALU op; full sum = lo + hi, wave-wide.
//   * Trans merge: one exp2+rcp serves sigmoid of r (low lanes) AND z (high
//     lanes) on sel = hi ? az : ar; one more swap redistributes -> r_all,z_all.
//     4 trans/step/row (vs R11's ~7 per 2 rows).
//   * Seeds (x-terms + biases) enter via per-lane MASKED constants (zero in
//     the non-owning half) -> no cndmasks on the seed path.
//   * h broadcast: all 64 lanes ds_write_b16 their h copy (64 slots); each
//     half reads only its 16 h values = 2x broadcast ds_read_b128.
//
// Kept from R11: weights f16 packed + pre-scaled into exp2 domain (r/z by
// -log2e, n by 2log2e), pinned; sigmoid = rcp(1+exp2(.)); tanh via exp2;
// x staged in LDS f32, vf4 per 4 steps, prefetched; x-FMAs hoisted.

typedef float vf2 __attribute__((ext_vector_type(2)));
typedef float vf4 __attribute__((ext_vector_type(4)));
typedef _Float16 f16;
typedef f16 h2 __attribute__((ext_vector_type(2)));
typedef f16 h8 __attribute__((ext_vector_type(8)));

#define TT 512
#define HH 32

// inline-asm defs are not rematerializable: forces a real VGPR def here.
#define PIN(v) asm volatile("" : "+v"(v))

#define LOG2E 1.44269504f

__device__ __forceinline__ float fast_sigm(float a) {   // sigmoid(a)
  return __builtin_amdgcn_rcpf(1.0f + __builtin_amdgcn_exp2f(-LOG2E * a));
}
__device__ __forceinline__ float fast_tanh(float a) {   // tanh(a)
  return __builtin_fmaf(-2.0f,
      __builtin_amdgcn_rcpf(1.0f + __builtin_amdgcn_exp2f(2.0f * LOG2E * a)),
      1.0f);
}

// (LO,HI) = (row0-broadcast, row1-broadcast) of X across the 32-lane halves.
// v_permlane32_swap_b32 vdst,vsrc: vdst.row1 <-> vsrc.row0. With both = X:
//   new vdst = [X.row0, X.row0], new vsrc = [X.row1, X.row1].
#define SWAP2(LO, HI, X) \
  float LO = (X), HI = (X); PIN(HI); \
  asm volatile("v_permlane32_swap_b32 %0, %1" : "+v"(LO), "+v"(HI))

__device__ __forceinline__ h2 pack_h2(vf2 a, float s) {
  h2 r = {(f16)(a.x * s), (f16)(a.y * s)};
  return r;
}

// load 8 packed-f16 h2 regs = this lane's 16-wide k-slice of one W_hh row,
// pre-scaled, pinned.  Base is in vf2 units; kb = 8*hi selects the k-half.
#define LDW8(P, BASE, S) \
  h2 P##0=pack_h2(Wp[(BASE)+kb+0],(S)), P##1=pack_h2(Wp[(BASE)+kb+1],(S)), \
     P##2=pack_h2(Wp[(BASE)+kb+2],(S)), P##3=pack_h2(Wp[(BASE)+kb+3],(S)), \
     P##4=pack_h2(Wp[(BASE)+kb+4],(S)), P##5=pack_h2(Wp[(BASE)+kb+5],(S)), \
     P##6=pack_h2(Wp[(BASE)+kb+6],(S)), P##7=pack_h2(Wp[(BASE)+kb+7],(S)); \
  PIN(P##0);PIN(P##1);PIN(P##2);PIN(P##3);PIN(P##4);PIN(P##5);PIN(P##6);PIN(P##7)

// 8 v_dot2_f32_f16 of (q0..q7).(P0..P7) into two chains; returns their sum.
#define FDOT8(OUT, P, SEED) \
  float OUT; { \
    float c0 = __builtin_amdgcn_fdot2(q0, P##0, (SEED), false); \
    float c1 = __builtin_amdgcn_fdot2(q1, P##1, 0.0f, false); \
    c0 = __builtin_amdgcn_fdot2(q2, P##2, c0, false); \
    c1 = __builtin_amdgcn_fdot2(q3, P##3, c1, false); \
    c0 = __builtin_amdgcn_fdot2(q4, P##4, c0, false); \
    c1 = __builtin_amdgcn_fdot2(q5, P##5, c1, false); \
    c0 = __builtin_amdgcn_fdot2(q6, P##6, c0, false); \
    c1 = __builtin_amdgcn_fdot2(q7, P##7, c1, false); \
    OUT = c0 + c1; }

__global__ __launch_bounds__(512)
__attribute__((amdgpu_waves_per_eu(2)))
void gru_bidir_head(const float* __restrict__ X,
                    const float* __restrict__ Wih_f, const float* __restrict__ Whh_f,
                    const float* __restrict__ bih_f, const float* __restrict__ bhh_f,
                    const float* __restrict__ Wih_b,
                    const float* __restrict__ bih_b, const float* __restrict__ bhh_b,
                    const float* __restrict__ W1, const float* __restrict__ b1,
                    const float* __restrict__ W2, const float* __restrict__ b2,
                    float* __restrict__ out)
{
  __shared__ float xbuf[8][TT];        // staged input rows (16 KB)
  __shared__ f16   hbuf[8][64];        // h copies: [0:32)=low half, [32:64)=high (1 KB)
  __shared__ float obuf[8][64];        // [row][h_f(32) | h_b(32)] (2 KB)

  const int lane = threadIdx.x & 63;
  const int g    = lane & 31;          // output index within the row
  const int hi   = lane >> 5;          // 0 = k-low half, 1 = k-high half
  const int kb   = 8 * hi;             // k-slice base in vf2 units
  const int rs   = threadIdx.x >> 6;   // row slot in block (0..7)
  const int b    = (blockIdx.x << 3) + rs;

  // --- stage this row of X into LDS (2 x vf4 per lane, coalesced) ---
  const vf4* Xr4 = (const vf4*)(X + (size_t)b * TT);
  vf4* xb4 = (vf4*)&xbuf[rs][0];
  #pragma unroll
  for (int q = 0; q < 2; ++q) xb4[lane + 64 * q] = Xr4[lane + 64 * q];

  // --- per-lane weights: this lane's 16-wide k-slice of W_hh rows g (r),
  //     32+g (z), 64+g (n); exp2-domain scaled, packed f16, pinned (24 VGPRs)
  const vf2* Wp = (const vf2*)Whh_f;   // row stride = 16 vf2
  const float s1 = -LOG2E;             // r,z: sigmoid domain (negated)
  const float s2 = 2.0f * LOG2E;       // n: tanh domain
  LDW8(Wr, (g)        * 16, s1);
  LDW8(Wz, (HH + g)   * 16, s1);
  LDW8(Wn, (2*HH + g) * 16, s2);

  // masked per-lane constants: seeds live only in the owning half.
  const float xwr_m = hi ? 0.0f : Wih_f[g] * s1;
  const float cbr_m = hi ? 0.0f : (bih_f[g] + bhh_f[g]) * s1;
  const float xwz_m = hi ? (Wih_f[HH + g] * s1) : 0.0f;
  const float cbz_m = hi ? ((bih_f[HH + g] + bhh_f[HH + g]) * s1) : 0.0f;
  const float cbh_m = hi ? 0.0f : bhh_f[2*HH + g] * s2;  // n: b_hh (inside r*(.))
  const float xwn   = Wih_f[2*HH + g] * s2;              // n x-term: all lanes
  const float cbn   = bih_f[2*HH + g] * s2;

  float h = 0.0f;
  hbuf[rs][lane] = (f16)0.0f;
  __builtin_amdgcn_wave_barrier();

  // this half's 16 h values: low reads hbuf[0:16), high reads hbuf[48:64)
  const h8* hv = (const h8*)(&hbuf[rs][0] + hi * 48);
  const vf4* xv = (const vf4*)&xbuf[rs][0];
  vf4 x4 = xv[0];

  #pragma unroll 1
  for (int tg = 0; tg < TT / 4; ++tg) {
    const vf4 x4n = xv[tg + 1 < TT / 4 ? tg + 1 : tg];   // off critical path

    // hoist x-dependent seeds for the 4 sub-steps (off the serial chain)
    float sr0 = __builtin_fmaf(x4.x, xwr_m, cbr_m), sz0 = __builtin_fmaf(x4.x, xwz_m, cbz_m),
          sn0 = __builtin_fmaf(x4.x, xwn, cbn);
    float sr1 = __builtin_fmaf(x4.y, xwr_m, cbr_m), sz1 = __builtin_fmaf(x4.y, xwz_m, cbz_m),
          sn1 = __builtin_fmaf(x4.y, xwn, cbn);
    float sr2 = __builtin_fmaf(x4.z, xwr_m, cbr_m), sz2 = __builtin_fmaf(x4.z, xwz_m, cbz_m),
          sn2 = __builtin_fmaf(x4.z, xwn, cbn);
    float sr3 = __builtin_fmaf(x4.w, xwr_m, cbr_m), sz3 = __builtin_fmaf(x4.w, xwz_m, cbz_m),
          sn3 = __builtin_fmaf(x4.w, xwn, cbn);

    #pragma unroll
    for (int u = 0; u < 4; ++u) {
      const float sr = (u == 0) ? sr0 : (u == 1) ? sr1 : (u == 2) ? sr2 : sr3;
      const float sz = (u == 0) ? sz0 : (u == 1) ? sz1 : (u == 2) ? sz2 : sz3;
      const float sn = (u == 0) ? sn0 : (u == 1) ? sn1 : (u == 2) ? sn2 : sn3;

      // this half's 16 h (f16): 2 broadcast ds_read_b128, conflict-free
      const h8 H0 = hv[0], H1 = hv[1];
      const h2 q0 = {H0[0], H0[1]}, q1 = {H0[2], H0[3]},
               q2 = {H0[4], H0[5]}, q3 = {H0[6], H0[7]},
               q4 = {H1[0], H1[1]}, q5 = {H1[2], H1[3]},
               q6 = {H1[4], H1[5]}, q7 = {H1[6], H1[7]};

      FDOT8(Pr, Wr, sr);                  // k-half partial of r[g] (+seed in low)
      FDOT8(Pz, Wz, sz);                  // k-half partial of z[g] (+seed in high)
      FDOT8(Pn, Wn, cbh_m);               // k-half partial of n-dot (+b_hh in low)

      // cross-half combines: full sums, wave-wide
      SWAP2(rlo, rhi, Pr);  const float ar = rlo + rhi;
      SWAP2(zlo, zhi, Pz);  const float az = zlo + zhi;
      SWAP2(nlo, nhi, Pn);  const float an = nlo + nhi;

      // merged sigmoid: low lanes evaluate r, high lanes z, one exp2+rcp
      const float sel = hi ? az : ar;
      const float S = __builtin_amdgcn_rcpf(1.0f + __builtin_amdgcn_exp2f(sel));
      SWAP2(rS, zS, S);                   // rS = r (all lanes), zS = z (all lanes)

      const float y = __builtin_fmaf(rS, an, sn);
      const float n = __builtin_fmaf(-2.0f,
          __builtin_amdgcn_rcpf(1.0f + __builtin_amdgcn_exp2f(y)), 1.0f);
      h = __builtin_fmaf(zS, h - n, n);   // (1-z)*n + z*h, wave-wide

      hbuf[rs][lane] = (f16)h;            // both copies; 64 distinct slots
      __builtin_amdgcn_wave_barrier();    // wave-synchronous ordering
    }
    x4 = x4n;
  }

  // --- backward direction: exactly ONE GRU step from h0=0 on x[T-1] ---
  const float xl  = xbuf[rs][TT - 1];
  const float rb  = fast_sigm(__builtin_fmaf(xl, Wih_b[g],      bih_b[g]      + bhh_b[g]));
  const float zb  = fast_sigm(__builtin_fmaf(xl, Wih_b[HH + g], bih_b[HH + g] + bhh_b[HH + g]));
  const float xnb = __builtin_fmaf(xl, Wih_b[2*HH + g], bih_b[2*HH + g]);
  const float nb  = fast_tanh(__builtin_fmaf(rb, bhh_b[2*HH + g], xnb));
  const float hb  = nb - zb * nb;                // (1-zb)*nb + zb*0

  obuf[rs][lane] = hi ? hb : h;          // [h_f(32) | h_b(32)] (both wave-wide)
  __builtin_amdgcn_wave_barrier();

  // --- MLP head: sigmoid(W2 @ relu(W1 @ [h_f,h_b] + b1) + b2) ---
  const int j = lane & 15;               // 4 duplicate groups of 16
  const vf4* W1r = (const vf4*)(W1 + j * 64);
  const vf4* hc  = (const vf4*)&obuf[rs][0];
  vf4 a4 = W1r[0] * hc[0];
  #pragma unroll
  for (int q = 1; q < 16; ++q)
    a4 = __builtin_elementwise_fma(W1r[q], hc[q], a4);
  float acc = b1[j] + (a4.x + a4.y) + (a4.z + a4.w);
  float h1 = fmaxf(acc, 0.0f) * W2[j];
  h1 += __shfl_down(h1, 8, 16);
  h1 += __shfl_down(h1, 4, 16);
  h1 += __shfl_down(h1, 2, 16);
  h1 += __shfl_down(h1, 1, 16);
  if (lane == 0) out[b] = fast_sigm(h1 + b2[0]);
}

extern "C" void kernel_launch(void* const* d_in, const int* in_sizes, int n_in,
                              void* d_out, int out_size, void* d_ws, size_t ws_size,
                              hipStream_t stream) {
  const float* X     = (const float*)d_in[0];
  const float* Wih_f = (const float*)d_in[1];
  const float* Whh_f = (const float*)d_in[2];
  const float* bih_f = (const float*)d_in[3];
  const float* bhh_f = (const float*)d_in[4];
  const float* Wih_b = (const float*)d_in[5];
  // d_in[6] = W_hh_b: unused — backward direction runs exactly one step from h0=0.
  const float* bih_b = (const float*)d_in[7];
  const float* bhh_b = (const float*)d_in[8];
  const float* W1    = (const float*)d_in[9];
  const float* b1    = (const float*)d_in[10];
  const float* W2    = (const float*)d_in[11];
  const float* b2    = (const float*)d_in[12];
  float* out = (float*)d_out;

  // 2048 rows / 8 rows per 512-thread block = 256 blocks = 1 block/CU,
  // 2048 waves = 2 waves/SIMD (one row per 64-lane wave, K-split halves).
  gru_bidir_head<<<256, 512, 0, stream>>>(X, Wih_f, Whh_f, bih_f, bhh_f,
                                          Wih_b, bih_b, bhh_b, W1, b1, W2, b2, out);
}

// Round 3
// 216.938 us; speedup vs baseline: 1.0566x; 1.0566x over previous
//
#include <hip/hip_runtime.h>

// Bidirectional GRU (H=32, input=1, B=2048, T=512) + MLP head, fully fused.
//
// Reference takes out[:, -1, :] = concat(h_fwd after T steps, h_bwd after ONE
// step from h0=0 on x[T-1]) -> only the forward scan is sequential; W_hh_b is
// entirely unused.
//
// R14 = R13 with the register-budget bug fixed.
//
// R13 post-mortem: amdgpu_waves_per_eu(2) sets only a MIN -> the allocator
// targeted max occupancy, capped the kernel at 32 arch-VGPRs (rocprof:
// VGPR_Count=32, was 132) and cycled the ~70 live values through AGPRs with
// v_accvgpr_read/write in the inner loop (VALUBusy 70%, zero extra memory
// traffic, 171 us). The K-split structure itself never got a fair test.
// R14 pins waves_per_eu(2, 2): exactly 2 waves/SIMD, 256-VGPR budget each.
//
// Structure (unchanged from R13):
//   * One row per 64-lane wave, K-split halves: lane g (low) holds h[0:16]
//     and computes k-low partials of r,z,n for output g (24 fdot2); lane
//     g+32 holds h[16:32], k-high partials. 2048 rows -> 2048 waves =
//     2 waves/SIMD; each wave's LDS-roundtrip + chain stall hides under the
//     other wave's issue (waves are independent: no cross-wave barriers).
//   * Cross-half combine via v_permlane32_swap_b32: swap(x,x) = (row0-bcast,
//     row1-bcast) in one full-rate VALU op; full sum = lo + hi, wave-wide.
//   * Trans merge: one exp2+rcp serves sigmoid of r (low lanes) AND z (high
//     lanes) on sel = hi ? az : ar; one more swap redistributes -> r_all,z_all.
//     4 trans/step/row.
//   * Seeds (x-terms + biases) enter via per-lane MASKED constants (zero in
//     the non-owning half) -> no cndmasks on the seed path.
//   * h broadcast: all 64 lanes ds_write_b16 their h copy (64 slots); each
//     half reads only its 16 h values = 2x broadcast ds_read_b128.
//
// Kept from R11: weights f16 packed + pre-scaled into exp2 domain (r/z by
// -log2e, n by 2log2e), pinned; sigmoid = rcp(1+exp2(.)); tanh via exp2;
// x staged in LDS f32, vf4 per 4 steps, prefetched; x-FMAs hoisted.

typedef float vf2 __attribute__((ext_vector_type(2)));
typedef float vf4 __attribute__((ext_vector_type(4)));
typedef _Float16 f16;
typedef f16 h2 __attribute__((ext_vector_type(2)));
typedef f16 h8 __attribute__((ext_vector_type(8)));

#define TT 512
#define HH 32

// inline-asm defs are not rematerializable: forces a real VGPR def here.
#define PIN(v) asm volatile("" : "+v"(v))

#define LOG2E 1.44269504f

__device__ __forceinline__ float fast_sigm(float a) {   // sigmoid(a)
  return __builtin_amdgcn_rcpf(1.0f + __builtin_amdgcn_exp2f(-LOG2E * a));
}
__device__ __forceinline__ float fast_tanh(float a) {   // tanh(a)
  return __builtin_fmaf(-2.0f,
      __builtin_amdgcn_rcpf(1.0f + __builtin_amdgcn_exp2f(2.0f * LOG2E * a)),
      1.0f);
}

// (LO,HI) = (row0-broadcast, row1-broadcast) of X across the 32-lane halves.
// v_permlane32_swap_b32 vdst,vsrc: vdst.row1 <-> vsrc.row0. With both = X:
//   new vdst = [X.row0, X.row0], new vsrc = [X.row1, X.row1].
#define SWAP2(LO, HI, X) \
  float LO = (X), HI = (X); PIN(HI); \
  asm volatile("v_permlane32_swap_b32 %0, %1" : "+v"(LO), "+v"(HI))

__device__ __forceinline__ h2 pack_h2(vf2 a, float s) {
  h2 r = {(f16)(a.x * s), (f16)(a.y * s)};
  return r;
}

// load 8 packed-f16 h2 regs = this lane's 16-wide k-slice of one W_hh row,
// pre-scaled, pinned.  Base is in vf2 units; kb = 8*hi selects the k-half.
#define LDW8(P, BASE, S) \
  h2 P##0=pack_h2(Wp[(BASE)+kb+0],(S)), P##1=pack_h2(Wp[(BASE)+kb+1],(S)), \
     P##2=pack_h2(Wp[(BASE)+kb+2],(S)), P##3=pack_h2(Wp[(BASE)+kb+3],(S)), \
     P##4=pack_h2(Wp[(BASE)+kb+4],(S)), P##5=pack_h2(Wp[(BASE)+kb+5],(S)), \
     P##6=pack_h2(Wp[(BASE)+kb+6],(S)), P##7=pack_h2(Wp[(BASE)+kb+7],(S)); \
  PIN(P##0);PIN(P##1);PIN(P##2);PIN(P##3);PIN(P##4);PIN(P##5);PIN(P##6);PIN(P##7)

// 8 v_dot2_f32_f16 of (q0..q7).(P0..P7) into two chains; returns their sum.
#define FDOT8(OUT, P, SEED) \
  float OUT; { \
    float c0 = __builtin_amdgcn_fdot2(q0, P##0, (SEED), false); \
    float c1 = __builtin_amdgcn_fdot2(q1, P##1, 0.0f, false); \
    c0 = __builtin_amdgcn_fdot2(q2, P##2, c0, false); \
    c1 = __builtin_amdgcn_fdot2(q3, P##3, c1, false); \
    c0 = __builtin_amdgcn_fdot2(q4, P##4, c0, false); \
    c1 = __builtin_amdgcn_fdot2(q5, P##5, c1, false); \
    c0 = __builtin_amdgcn_fdot2(q6, P##6, c0, false); \
    c1 = __builtin_amdgcn_fdot2(q7, P##7, c1, false); \
    OUT = c0 + c1; }

__global__ __launch_bounds__(512)
__attribute__((amdgpu_waves_per_eu(2, 2)))
void gru_bidir_head(const float* __restrict__ X,
                    const float* __restrict__ Wih_f, const float* __restrict__ Whh_f,
                    const float* __restrict__ bih_f, const float* __restrict__ bhh_f,
                    const float* __restrict__ Wih_b,
                    const float* __restrict__ bih_b, const float* __restrict__ bhh_b,
                    const float* __restrict__ W1, const float* __restrict__ b1,
                    const float* __restrict__ W2, const float* __restrict__ b2,
                    float* __restrict__ out)
{
  __shared__ float xbuf[8][TT];        // staged input rows (16 KB)
  __shared__ f16   hbuf[8][64];        // h copies: [0:32)=low half, [32:64)=high (1 KB)
  __shared__ float obuf[8][64];        // [row][h_f(32) | h_b(32)] (2 KB)

  const int lane = threadIdx.x & 63;
  const int g    = lane & 31;          // output index within the row
  const int hi   = lane >> 5;          // 0 = k-low half, 1 = k-high half
  const int kb   = 8 * hi;             // k-slice base in vf2 units
  const int rs   = threadIdx.x >> 6;   // row slot in block (0..7)
  const int b    = (blockIdx.x << 3) + rs;

  // --- stage this row of X into LDS (2 x vf4 per lane, coalesced) ---
  const vf4* Xr4 = (const vf4*)(X + (size_t)b * TT);
  vf4* xb4 = (vf4*)&xbuf[rs][0];
  #pragma unroll
  for (int q = 0; q < 2; ++q) xb4[lane + 64 * q] = Xr4[lane + 64 * q];

  // --- per-lane weights: this lane's 16-wide k-slice of W_hh rows g (r),
  //     32+g (z), 64+g (n); exp2-domain scaled, packed f16, pinned (24 VGPRs)
  const vf2* Wp = (const vf2*)Whh_f;   // row stride = 16 vf2
  const float s1 = -LOG2E;             // r,z: sigmoid domain (negated)
  const float s2 = 2.0f * LOG2E;       // n: tanh domain
  LDW8(Wr, (g)        * 16, s1);
  LDW8(Wz, (HH + g)   * 16, s1);
  LDW8(Wn, (2*HH + g) * 16, s2);

  // masked per-lane constants: seeds live only in the owning half.
  const float xwr_m = hi ? 0.0f : Wih_f[g] * s1;
  const float cbr_m = hi ? 0.0f : (bih_f[g] + bhh_f[g]) * s1;
  const float xwz_m = hi ? (Wih_f[HH + g] * s1) : 0.0f;
  const float cbz_m = hi ? ((bih_f[HH + g] + bhh_f[HH + g]) * s1) : 0.0f;
  const float cbh_m = hi ? 0.0f : bhh_f[2*HH + g] * s2;  // n: b_hh (inside r*(.))
  const float xwn   = Wih_f[2*HH + g] * s2;              // n x-term: all lanes
  const float cbn   = bih_f[2*HH + g] * s2;

  float h = 0.0f;
  hbuf[rs][lane] = (f16)0.0f;
  __builtin_amdgcn_wave_barrier();

  // this half's 16 h values: low reads hbuf[0:16), high reads hbuf[48:64)
  const h8* hv = (const h8*)(&hbuf[rs][0] + hi * 48);
  const vf4* xv = (const vf4*)&xbuf[rs][0];
  vf4 x4 = xv[0];

  #pragma unroll 1
  for (int tg = 0; tg < TT / 4; ++tg) {
    const vf4 x4n = xv[tg + 1 < TT / 4 ? tg + 1 : tg];   // off critical path

    // hoist x-dependent seeds for the 4 sub-steps (off the serial chain)
    float sr0 = __builtin_fmaf(x4.x, xwr_m, cbr_m), sz0 = __builtin_fmaf(x4.x, xwz_m, cbz_m),
          sn0 = __builtin_fmaf(x4.x, xwn, cbn);
    float sr1 = __builtin_fmaf(x4.y, xwr_m, cbr_m), sz1 = __builtin_fmaf(x4.y, xwz_m, cbz_m),
          sn1 = __builtin_fmaf(x4.y, xwn, cbn);
    float sr2 = __builtin_fmaf(x4.z, xwr_m, cbr_m), sz2 = __builtin_fmaf(x4.z, xwz_m, cbz_m),
          sn2 = __builtin_fmaf(x4.z, xwn, cbn);
    float sr3 = __builtin_fmaf(x4.w, xwr_m, cbr_m), sz3 = __builtin_fmaf(x4.w, xwz_m, cbz_m),
          sn3 = __builtin_fmaf(x4.w, xwn, cbn);

    #pragma unroll
    for (int u = 0; u < 4; ++u) {
      const float sr = (u == 0) ? sr0 : (u == 1) ? sr1 : (u == 2) ? sr2 : sr3;
      const float sz = (u == 0) ? sz0 : (u == 1) ? sz1 : (u == 2) ? sz2 : sz3;
      const float sn = (u == 0) ? sn0 : (u == 1) ? sn1 : (u == 2) ? sn2 : sn3;

      // this half's 16 h (f16): 2 broadcast ds_read_b128, conflict-free
      const h8 H0 = hv[0], H1 = hv[1];
      const h2 q0 = {H0[0], H0[1]}, q1 = {H0[2], H0[3]},
               q2 = {H0[4], H0[5]}, q3 = {H0[6], H0[7]},
               q4 = {H1[0], H1[1]}, q5 = {H1[2], H1[3]},
               q6 = {H1[4], H1[5]}, q7 = {H1[6], H1[7]};

      FDOT8(Pr, Wr, sr);                  // k-half partial of r[g] (+seed in low)
      FDOT8(Pz, Wz, sz);                  // k-half partial of z[g] (+seed in high)
      FDOT8(Pn, Wn, cbh_m);               // k-half partial of n-dot (+b_hh in low)

      // cross-half combines: full sums, wave-wide
      SWAP2(rlo, rhi, Pr);  const float ar = rlo + rhi;
      SWAP2(zlo, zhi, Pz);  const float az = zlo + zhi;
      SWAP2(nlo, nhi, Pn);  const float an = nlo + nhi;

      // merged sigmoid: low lanes evaluate r, high lanes z, one exp2+rcp
      const float sel = hi ? az : ar;
      const float S = __builtin_amdgcn_rcpf(1.0f + __builtin_amdgcn_exp2f(sel));
      SWAP2(rS, zS, S);                   // rS = r (all lanes), zS = z (all lanes)

      const float y = __builtin_fmaf(rS, an, sn);
      const float n = __builtin_fmaf(-2.0f,
          __builtin_amdgcn_rcpf(1.0f + __builtin_amdgcn_exp2f(y)), 1.0f);
      h = __builtin_fmaf(zS, h - n, n);   // (1-z)*n + z*h, wave-wide

      hbuf[rs][lane] = (f16)h;            // both copies; 64 distinct slots
      __builtin_amdgcn_wave_barrier();    // wave-synchronous ordering
    }
    x4 = x4n;
  }

  // --- backward direction: exactly ONE GRU step from h0=0 on x[T-1] ---
  const float xl  = xbuf[rs][TT - 1];
  const float rb  = fast_sigm(__builtin_fmaf(xl, Wih_b[g],      bih_b[g]      + bhh_b[g]));
  const float zb  = fast_sigm(__builtin_fmaf(xl, Wih_b[HH + g], bih_b[HH + g] + bhh_b[HH + g]));
  const float xnb = __builtin_fmaf(xl, Wih_b[2*HH + g], bih_b[2*HH + g]);
  const float nb  = fast_tanh(__builtin_fmaf(rb, bhh_b[2*HH + g], xnb));
  const float hb  = nb - zb * nb;                // (1-zb)*nb + zb*0

  obuf[rs][lane] = hi ? hb : h;          // [h_f(32) | h_b(32)] (both wave-wide)
  __builtin_amdgcn_wave_barrier();

  // --- MLP head: sigmoid(W2 @ relu(W1 @ [h_f,h_b] + b1) + b2) ---
  const int j = lane & 15;               // 4 duplicate groups of 16
  const vf4* W1r = (const vf4*)(W1 + j * 64);
  const vf4* hc  = (const vf4*)&obuf[rs][0];
  vf4 a4 = W1r[0] * hc[0];
  #pragma unroll
  for (int q = 1; q < 16; ++q)
    a4 = __builtin_elementwise_fma(W1r[q], hc[q], a4);
  float acc = b1[j] + (a4.x + a4.y) + (a4.z + a4.w);
  float h1 = fmaxf(acc, 0.0f) * W2[j];
  h1 += __shfl_down(h1, 8, 16);
  h1 += __shfl_down(h1, 4, 16);
  h1 += __shfl_down(h1, 2, 16);
  h1 += __shfl_down(h1, 1, 16);
  if (lane == 0) out[b] = fast_sigm(h1 + b2[0]);
}

extern "C" void kernel_launch(void* const* d_in, const int* in_sizes, int n_in,
                              void* d_out, int out_size, void* d_ws, size_t ws_size,
                              hipStream_t stream) {
  const float* X     = (const float*)d_in[0];
  const float* Wih_f = (const float*)d_in[1];
  const float* Whh_f = (const float*)d_in[2];
  const float* bih_f = (const float*)d_in[3];
  const float* bhh_f = (const float*)d_in[4];
  const float* Wih_b = (const float*)d_in[5];
  // d_in[6] = W_hh_b: unused — backward direction runs exactly one step from h0=0.
  const float* bih_b = (const float*)d_in[7];
  const float* bhh_b = (const float*)d_in[8];
  const float* W1    = (const float*)d_in[9];
  const float* b1    = (const float*)d_in[10];
  const float* W2    = (const float*)d_in[11];
  const float* b2    = (const float*)d_in[12];
  float* out = (float*)d_out;

  // 2048 rows / 8 rows per 512-thread block = 256 blocks = 1 block/CU,
  // 2048 waves = 2 waves/SIMD (one row per 64-lane wave, K-split halves).
  gru_bidir_head<<<256, 512, 0, stream>>>(X, Wih_f, Whh_f, bih_f, bhh_f,
                                          Wih_b, bih_b, bhh_b, W1, b1, W2, b2, out);
}